// Round 11
// baseline (1743.742 us; speedup 1.0000x reference)
//
#include <hip/hip_runtime.h>
#include <cmath>

// ---------------------------------------------------------------------------
// CausalStream: conv frontend (4 dilated causal convs) -> folded enc+ip GEMM
// -> sequential gelu-SSM scan -> pooled/cls heads + metanet/frontdoor path.
// B=32, D=6, T=2048, FH=128, ENC=128, H=256, CONF=64, NC=10, K=5
// Scan rewritten from MFMA (16x M-broadcast waste, 512cy/step pipe floor) to
// v_dot2_f32_f16 GEMV (64 useful MACs/cy/SIMD, 2x the MFMA useful rate).
// ---------------------------------------------------------------------------

typedef __bf16 bf16_t;
typedef bf16_t bf16x8 __attribute__((ext_vector_type(8)));
typedef float f32x4 __attribute__((ext_vector_type(4)));
typedef _Float16 f16_t;
typedef f16_t f16x2 __attribute__((ext_vector_type(2)));
typedef f16_t f16x8 __attribute__((ext_vector_type(8)));

__device__ __forceinline__ f32x4 mfma16(bf16x8 a, bf16x8 b, f32x4 c) {
  return __builtin_amdgcn_mfma_f32_16x16x32_bf16(a, b, c, 0, 0, 0);
}

// 2-way f16 dot with f32 accumulate: v_dot2_f32_f16 (2cy wave64 issue).
__device__ __forceinline__ float fdot2(f16x2 a, f16x2 b, float c) {
#if __has_builtin(__builtin_amdgcn_fdot2)
  return __builtin_amdgcn_fdot2(a, b, c, false);
#else
  asm("v_dot2_f32_f16 %0, %1, %2, %0" : "+v"(c) : "v"(a), "v"(b));
  return c;
#endif
}

// Fast erf-gelu: Abramowitz-Stegun 7.1.26 (|erf err| <= 1.5e-7), branch-free.
__device__ __forceinline__ float gelu_f(float x) {
  float a = x * 0.70710678118654752440f;
  float z = fabsf(a);
  float t = __builtin_amdgcn_rcpf(1.0f + 0.3275911f * z);
  float p = t * (0.254829592f +
            t * (-0.284496736f +
            t * (1.421413741f +
            t * (-1.453152027f +
            t * 1.061405429f))));
  float e = __expf(-z * z);
  float erf_a = __builtin_copysignf(1.0f - p * e, a);
  return 0.5f * x * (1.0f + erf_a);
}

// ---------------------------------------------------------------------------
// k_prep: conv-weight repack (blocks 0..975) + enc/ip fold (blocks 976..1103).
// ---------------------------------------------------------------------------
__global__ void k_prep(const float* __restrict__ w0, const float* __restrict__ w1,
                       const float* __restrict__ w2, const float* __restrict__ w3,
                       const float* __restrict__ ip_w, const float* __restrict__ enc_w,
                       const float* __restrict__ enc_b, const float* __restrict__ ip_b,
                       const float* __restrict__ sbias,
                       bf16_t* __restrict__ wb0, bf16_t* __restrict__ wb1,
                       bf16_t* __restrict__ wb2, bf16_t* __restrict__ wb3,
                       bf16_t* __restrict__ wce, float* __restrict__ bce) {
  int bid = blockIdx.x;
  if (bid >= 976) {
    // W_ce[h][c] = sum_e ip_w[h][e]*enc_w[e][c]
    int idx = (bid - 976) * 256 + threadIdx.x;  // 0..32767
    int h = idx >> 7, c = idx & 127;
    float s = 0.f;
    for (int e = 0; e < 128; ++e) s += ip_w[h * 128 + e] * enc_w[e * 128 + c];
    wce[h * 128 + c] = (bf16_t)s;
    if (c == 0) {
      float bv = 0.f;
      for (int e = 0; e < 128; ++e) bv += ip_w[h * 128 + e] * enc_b[e];
      bce[h] = bv + ip_b[h] + sbias[h];
    }
    return;
  }
  int idx = bid * 256 + threadIdx.x;
  if (idx < 128 * 32) {
    int o = idx >> 5, k = idx & 31;
    float v = 0.f;
    if (k < 30) { int i = k / 5, kk = k - i * 5; v = w0[(o * 6 + i) * 5 + kk]; }
    wb0[idx] = (bf16_t)v;
    return;
  }
  int e = idx - 128 * 32;
  if (e < 3 * 5 * 128 * 128) {
    int layer = e / (5 * 128 * 128);
    int r = e - layer * (5 * 128 * 128);
    int ks = r / 16384;
    int o = (r >> 7) & 127;
    int i = r & 127;
    const float* w = layer == 0 ? w1 : layer == 1 ? w2 : w3;
    bf16_t* wb = layer == 0 ? wb1 : layer == 1 ? wb2 : wb3;
    wb[r] = (bf16_t)w[(o * 128 + i) * 5 + ks];
  }
}

// ---------------------------------------------------------------------------
// conv0: M (B,6,T) fp32 -> act (B,T,128) bf16.  K-dim = 6*5 padded to 32.
// ---------------------------------------------------------------------------
__global__ __launch_bounds__(256) void k_conv0(const float* __restrict__ M,
                                               const bf16_t* __restrict__ wb0,
                                               const float* __restrict__ b0,
                                               bf16_t* __restrict__ out) {
  __shared__ float raw[6][136];
  __shared__ bf16_t Xe[128 * 40];
  const int tid = threadIdx.x;
  const int b = blockIdx.y, t0 = blockIdx.x * 128;
  for (int id = tid; id < 6 * 132; id += 256) {
    int i = id / 132, j = id - i * 132;
    int t = t0 - 4 + j;
    raw[i][j] = (t >= 0) ? M[((size_t)b * 6 + i) * 2048 + t] : 0.f;
  }
  __syncthreads();
  for (int id = tid; id < 128 * 32; id += 256) {
    int tl = id >> 5, k = id & 31;
    float v = 0.f;
    if (k < 30) { int i = k / 5, kk = k - i * 5; v = raw[i][tl + kk]; }
    Xe[tl * 40 + k] = (bf16_t)v;
  }
  __syncthreads();
  const int w = tid >> 6, lane = tid & 63, q = lane >> 4, l15 = lane & 15;
  const int k0 = q * 8;
  const f32x4 z4 = {0.f, 0.f, 0.f, 0.f};
  f32x4 acc[2][8];
#pragma unroll
  for (int mt = 0; mt < 2; ++mt)
#pragma unroll
    for (int nt = 0; nt < 8; ++nt) acc[mt][nt] = z4;
  bf16x8 af[2];
#pragma unroll
  for (int mt = 0; mt < 2; ++mt)
    af[mt] = *(const bf16x8*)&Xe[(w * 32 + mt * 16 + l15) * 40 + k0];
#pragma unroll
  for (int nt = 0; nt < 8; ++nt) {
    bf16x8 bf = *(const bf16x8*)&wb0[(nt * 16 + l15) * 32 + k0];
#pragma unroll
    for (int mt = 0; mt < 2; ++mt) acc[mt][nt] = mfma16(af[mt], bf, acc[mt][nt]);
  }
#pragma unroll
  for (int nt = 0; nt < 8; ++nt) {
    const int o = nt * 16 + l15;
    const float bias = b0[o];
#pragma unroll
    for (int mt = 0; mt < 2; ++mt) {
#pragma unroll
      for (int r = 0; r < 4; ++r) {
        int t = t0 + w * 32 + mt * 16 + q * 4 + r;
        float v = acc[mt][nt][r] + bias;
        out[((size_t)b * 2048 + t) * 128 + o] = (bf16_t)(v > 0.f ? v : 0.f);
      }
    }
  }
}

// ---------------------------------------------------------------------------
// conv layers 1..3 (verified 128-tile): act (B,T,128) bf16 -> act bf16,
// kernel 5, dilation DIL, causal.  Implicit GEMM.
// ---------------------------------------------------------------------------
template <int DIL>
__global__ __launch_bounds__(256) void k_conv(const bf16_t* __restrict__ in,
                                              const bf16_t* __restrict__ wb,
                                              const float* __restrict__ bias,
                                              bf16_t* __restrict__ out) {
  __shared__ bf16_t Xs[160 * 136];  // rows r <-> t = t0 + r - 32, pitch-padded
  const int tid = threadIdx.x;
  const int b = blockIdx.y, t0 = blockIdx.x * 128;
  const bf16_t* src = in + (size_t)b * 2048 * 128;
  for (int id = tid; id < 160 * 16; id += 256) {
    int r = id >> 4, ck = id & 15;
    int t = t0 + r - 32;
    int4 v = make_int4(0, 0, 0, 0);
    if (t >= 0) v = *(const int4*)(src + (size_t)t * 128 + ck * 8);
    *(int4*)&Xs[r * 136 + ck * 8] = v;
  }
  __syncthreads();
  const int w = tid >> 6, lane = tid & 63, q = lane >> 4, l15 = lane & 15;
  const f32x4 z4 = {0.f, 0.f, 0.f, 0.f};
  f32x4 acc[2][8];
#pragma unroll
  for (int mt = 0; mt < 2; ++mt)
#pragma unroll
    for (int nt = 0; nt < 8; ++nt) acc[mt][nt] = z4;
#pragma unroll
  for (int ks = 0; ks < 5; ++ks) {
    const int shift = (4 - ks) * DIL;
#pragma unroll
    for (int kt = 0; kt < 4; ++kt) {
      const int k0 = kt * 32 + q * 8;
      bf16x8 af[2];
#pragma unroll
      for (int mt = 0; mt < 2; ++mt)
        af[mt] = *(const bf16x8*)&Xs[(32 + w * 32 + mt * 16 + l15 - shift) * 136 + k0];
#pragma unroll
      for (int nt = 0; nt < 8; ++nt) {
        bf16x8 bf = *(const bf16x8*)&wb[((size_t)ks * 128 + nt * 16 + l15) * 128 + k0];
#pragma unroll
        for (int mt = 0; mt < 2; ++mt) acc[mt][nt] = mfma16(af[mt], bf, acc[mt][nt]);
      }
    }
  }
#pragma unroll
  for (int nt = 0; nt < 8; ++nt) {
    const int o = nt * 16 + l15;
    const float bv = bias[o];
#pragma unroll
    for (int mt = 0; mt < 2; ++mt) {
#pragma unroll
      for (int r = 0; r < 4; ++r) {
        int t = t0 + w * 32 + mt * 16 + q * 4 + r;
        float v = acc[mt][nt][r] + bv;
        out[((size_t)b * 2048 + t) * 128 + o] = (bf16_t)(v > 0.f ? v : 0.f);
      }
    }
  }
}

// ---------------------------------------------------------------------------
// u-GEMM: u[b][t][h] = act3[b][t][:] @ W_ce[h][:] + b_ce[h]   (bf16 out)
// ---------------------------------------------------------------------------
__global__ __launch_bounds__(256) void k_ugemm(const bf16_t* __restrict__ in,
                                               const bf16_t* __restrict__ wce,
                                               const float* __restrict__ bce,
                                               bf16_t* __restrict__ u) {
  __shared__ bf16_t Xs[128 * 136];
  const int tid = threadIdx.x;
  const int b = blockIdx.y, t0 = blockIdx.x * 128, hh = blockIdx.z;
  const bf16_t* src = in + (size_t)b * 2048 * 128;
  for (int id = tid; id < 128 * 16; id += 256) {
    int r = id >> 4, ck = id & 15;
    *(int4*)&Xs[r * 136 + ck * 8] = *(const int4*)(src + (size_t)(t0 + r) * 128 + ck * 8);
  }
  __syncthreads();
  const int w = tid >> 6, lane = tid & 63, q = lane >> 4, l15 = lane & 15;
  const f32x4 z4 = {0.f, 0.f, 0.f, 0.f};
  f32x4 acc[2][8];
#pragma unroll
  for (int mt = 0; mt < 2; ++mt)
#pragma unroll
    for (int nt = 0; nt < 8; ++nt) acc[mt][nt] = z4;
#pragma unroll
  for (int kt = 0; kt < 4; ++kt) {
    const int k0 = kt * 32 + q * 8;
    bf16x8 af[2];
#pragma unroll
    for (int mt = 0; mt < 2; ++mt)
      af[mt] = *(const bf16x8*)&Xs[(w * 32 + mt * 16 + l15) * 136 + k0];
#pragma unroll
    for (int nt = 0; nt < 8; ++nt) {
      bf16x8 bf = *(const bf16x8*)&wce[((size_t)hh * 128 + nt * 16 + l15) * 128 + k0];
#pragma unroll
      for (int mt = 0; mt < 2; ++mt) acc[mt][nt] = mfma16(af[mt], bf, acc[mt][nt]);
    }
  }
#pragma unroll
  for (int nt = 0; nt < 8; ++nt) {
    const int h = hh * 128 + nt * 16 + l15;
    const float bv = bce[h];
#pragma unroll
    for (int mt = 0; mt < 2; ++mt) {
#pragma unroll
      for (int r = 0; r < 4; ++r) {
        int t = t0 + w * 32 + mt * 16 + q * 4 + r;
        u[((size_t)b * 2048 + t) * 256 + h] = (bf16_t)(acc[mt][nt][r] + bv);
      }
    }
  }
}

// ---------------------------------------------------------------------------
// Sequential scan via v_dot2_f32_f16 GEMV: h_{t} = gelu(A @ h_{t-1} + u_t).
// One block per sample; thread c owns output column c.
//  - A[:,c] register-resident as 32 x f16x8 (128 VGPRs, replaces bfr).
//  - h state in LDS as f16 (better mantissa than bf16); per step each thread
//    reads all 256 h via 32 uniform-address ds_read_b128 (broadcast,
//    conflict-free) and issues 128 fdot2 into 4 rotating f32 accumulators
//    (2cy issue, 4-chain covers the 4cy dependent-FMA latency).
//  - useful-MAC rate 64/cy/SIMD vs MFMA path's 32 (16x M-broadcast waste),
//    so the math phase drops ~512 -> ~256-320 cy/step.
//  - verified sync protocol kept: lgkm-only barrier + 2-deep u prefetch.
// ---------------------------------------------------------------------------
__global__ __launch_bounds__(256, 1) void k_scan(const float* __restrict__ Am,
                                                 const bf16_t* __restrict__ u,
                                                 float* __restrict__ hbarOut) {
  __shared__ f16_t hb[2][256];
  const int b = blockIdx.x;
  const int c = threadIdx.x;  // this thread's output column

  // A column: Ac[k8][e] = A[c][k8*8+e] as f16.
  f16x8 Ac[32];
#pragma unroll
  for (int k8 = 0; k8 < 32; ++k8) {
    const float* ap = Am + (size_t)c * 256 + k8 * 8;
    f16x8 v;
#pragma unroll
    for (int e = 0; e < 8; ++e) v[e] = (f16_t)ap[e];
    Ac[k8] = v;
  }
  hb[0][c] = (f16_t)0.f;
  hb[1][c] = (f16_t)0.f;
  const bf16_t* up = u + (size_t)b * 2048 * 256 + c;
  float hbar = 0.f;
  bf16_t ua = up[0];
  bf16_t ub = up[256];
  __syncthreads();

#define SCAN_STEP(RD, WR, UREG)                                   \
  {                                                               \
    float a0 = 0.f, a1 = 0.f, a2 = 0.f, a3 = 0.f;                 \
    _Pragma("unroll")                                             \
    for (int k8 = 0; k8 < 32; ++k8) {                             \
      f16x8 h8 = *(const f16x8*)&hb[RD][k8 * 8];                  \
      f16x8 A8 = Ac[k8];                                          \
      f16x2 ha = {h8[0], h8[1]}, Aa = {A8[0], A8[1]};             \
      f16x2 hbp = {h8[2], h8[3]}, Ab = {A8[2], A8[3]};            \
      f16x2 hc = {h8[4], h8[5]}, Acp = {A8[4], A8[5]};            \
      f16x2 hd = {h8[6], h8[7]}, Ad = {A8[6], A8[7]};             \
      a0 = fdot2(Aa, ha, a0);                                     \
      a1 = fdot2(Ab, hbp, a1);                                    \
      a2 = fdot2(Acp, hc, a2);                                    \
      a3 = fdot2(Ad, hd, a3);                                     \
    }                                                             \
    float y = ((a0 + a1) + (a2 + a3)) + (float)(UREG);            \
    float g = gelu_f(y);                                          \
    hb[WR][c] = (f16_t)g;                                         \
    asm volatile("s_waitcnt lgkmcnt(0)" ::: "memory");            \
    __builtin_amdgcn_s_barrier();                                 \
    __builtin_amdgcn_sched_barrier(0);                            \
    hbar += g;                                                    \
  }

  for (int t = 0; t < 2048; t += 2) {
    bf16_t ua2 = (t + 2 < 2048) ? up[(size_t)(t + 2) * 256] : (bf16_t)0.f;
    SCAN_STEP(0, 1, ua)
    bf16_t ub2 = (t + 3 < 2048) ? up[(size_t)(t + 3) * 256] : (bf16_t)0.f;
    SCAN_STEP(1, 0, ub)
    ua = ua2;
    ub = ub2;
  }
#undef SCAN_STEP

  hbarOut[b * 256 + c] = hbar * (1.f / 2048.f);
}

// ---------------------------------------------------------------------------
// k_post: metanet stats + metanet/frontdoor MLPs + pooled/cls head, fused.
// One block per sample, 256 threads.  Runs after k_scan (needs hbar).
// ---------------------------------------------------------------------------
__global__ __launch_bounds__(256) void k_post(
    const float* __restrict__ M, const float* __restrict__ hbar,
    const float* __restrict__ w1, const float* __restrict__ b1,
    const float* __restrict__ w2, const float* __restrict__ b2,
    const float* __restrict__ w3, const float* __restrict__ b3,
    const float* __restrict__ f1, const float* __restrict__ fb1,
    const float* __restrict__ f2, const float* __restrict__ fb2,
    const float* __restrict__ op_w, const float* __restrict__ op_b,
    const float* __restrict__ cw1, const float* __restrict__ cb1,
    const float* __restrict__ cw2, const float* __restrict__ cb2,
    float* __restrict__ out) {
  const int b = blockIdx.x, tid = threadIdx.x;
  const int w = tid >> 6, lane = tid & 63;
  __shared__ float s12[12], z1[64], z2[128], ch[64], a1[128], adjs[256];
  __shared__ float hs[256], ps[256], hid[256];
  __shared__ float as_[4], ass_[4];
  // stats: mean & unbiased std per channel
  for (int c = 0; c < 6; ++c) {
    const float* p = M + ((size_t)b * 6 + c) * 2048;
    float s = 0.f, ss = 0.f;
    for (int t = tid; t < 2048; t += 256) { float v = p[t]; s += v; ss += v * v; }
    for (int o = 32; o > 0; o >>= 1) { s += __shfl_down(s, o, 64); ss += __shfl_down(ss, o, 64); }
    if (lane == 0) { as_[w] = s; ass_[w] = ss; }
    __syncthreads();
    if (tid == 0) {
      s = as_[0] + as_[1] + as_[2] + as_[3];
      ss = ass_[0] + ass_[1] + ass_[2] + ass_[3];
      float mean = s * (1.f / 2048.f);
      float var = (ss - 2048.f * mean * mean) * (1.f / 2047.f);
      if (var < 0.f) var = 0.f;
      s12[c] = mean;
      s12[6 + c] = sqrtf(var);
    }
    __syncthreads();
  }
  // metanet
  if (tid < 64) {
    float v = b1[tid];
    for (int e = 0; e < 12; ++e) v += w1[tid * 12 + e] * s12[e];
    z1[tid] = v > 0.f ? v : 0.f;
  }
  __syncthreads();
  if (tid < 128) {
    float v = b2[tid];
    for (int e = 0; e < 64; ++e) v += w2[tid * 64 + e] * z1[e];
    z2[tid] = v > 0.f ? v : 0.f;
  }
  __syncthreads();
  if (tid < 64) {
    float v = b3[tid];
    for (int e = 0; e < 128; ++e) v += w3[tid * 128 + e] * z2[e];
    ch[tid] = v;
    out[16704 + b * 64 + tid] = v;  // conf_hat
  }
  __syncthreads();
  if (tid < 128) {
    float v = fb1[tid];
    for (int e = 0; e < 64; ++e) v += f1[tid * 64 + e] * ch[e];
    a1[tid] = v > 0.f ? v : 0.f;
  }
  __syncthreads();
  {
    float v = fb2[tid];
    for (int e = 0; e < 128; ++e) v += f2[tid * 128 + e] * a1[e];
    adjs[tid] = v;  // self-read below, no sync needed
  }
  // head
  hs[tid] = hbar[b * 256 + tid];
  __syncthreads();
  float v = op_b[tid];
  for (int h = 0; h < 256; ++h) v += op_w[tid * 256 + h] * hs[h];
  out[320 + b * 256 + tid] = v;                    // pooled
  out[8512 + b * 256 + tid] = v - adjs[tid];       // corrected
  ps[tid] = v;
  __syncthreads();
  float hv = cb1[tid];
  for (int h = 0; h < 256; ++h) hv += cw1[tid * 256 + h] * ps[h];
  hid[tid] = hv > 0.f ? hv : 0.f;
  __syncthreads();
  if (tid < 10) {
    float lv = cb2[tid];
    for (int h = 0; h < 256; ++h) lv += cw2[tid * 256 + h] * hid[h];
    out[b * 10 + tid] = lv;  // logits
  }
}

// ---------------------------------------------------------------------------
extern "C" void kernel_launch(void* const* d_in, const int* in_sizes, int n_in,
                              void* d_out, int out_size, void* d_ws, size_t ws_size,
                              hipStream_t stream) {
  (void)in_sizes; (void)n_in; (void)out_size; (void)ws_size;
  const float* M    = (const float*)d_in[0];
  const float* w0   = (const float*)d_in[1];  const float* b0  = (const float*)d_in[2];
  const float* w1   = (const float*)d_in[3];  const float* b1  = (const float*)d_in[4];
  const float* w2   = (const float*)d_in[5];  const float* b2  = (const float*)d_in[6];
  const float* w3   = (const float*)d_in[7];  const float* b3  = (const float*)d_in[8];
  const float* encw = (const float*)d_in[9];  const float* encb = (const float*)d_in[10];
  const float* Am   = (const float*)d_in[11];
  const float* ipw  = (const float*)d_in[12]; const float* ipb = (const float*)d_in[13];
  const float* sb   = (const float*)d_in[14];
  const float* opw  = (const float*)d_in[15]; const float* opb = (const float*)d_in[16];
  const float* cw1  = (const float*)d_in[17]; const float* cb1 = (const float*)d_in[18];
  const float* cw2  = (const float*)d_in[19]; const float* cb2 = (const float*)d_in[20];
  const float* mw1  = (const float*)d_in[21]; const float* mb1 = (const float*)d_in[22];
  const float* mw2  = (const float*)d_in[23]; const float* mb2 = (const float*)d_in[24];
  const float* mw3  = (const float*)d_in[25]; const float* mb3 = (const float*)d_in[26];
  const float* fw1  = (const float*)d_in[27]; const float* fb1 = (const float*)d_in[28];
  const float* fw2  = (const float*)d_in[29]; const float* fb2 = (const float*)d_in[30];
  float* out = (float*)d_out;

  char* ws = (char*)d_ws;
  bf16_t* wb0  = (bf16_t*)(ws + 0);          // 8192
  bf16_t* wb1  = (bf16_t*)(ws + 8192);       // 163840
  bf16_t* wb2  = (bf16_t*)(ws + 172032);     // 163840
  bf16_t* wb3  = (bf16_t*)(ws + 335872);     // 163840
  bf16_t* wce  = (bf16_t*)(ws + 499712);     // 65536
  float*  bce  = (float*) (ws + 565248);     // 1024
  float*  hbar = (float*) (ws + 566272);     // 32768
  bf16_t* actA = (bf16_t*)(ws + 633856);     // 16 MB
  bf16_t* actB = (bf16_t*)(ws + 17411072);   // 16 MB
  bf16_t* u    = (bf16_t*)(ws + 34188288);   // 32 MB  (total ~64.6 MB)

  k_prep<<<1104, 256, 0, stream>>>(w0, w1, w2, w3, ipw, encw, encb, ipb, sb,
                                   wb0, wb1, wb2, wb3, wce, bce);
  k_conv0<<<dim3(16, 32), 256, 0, stream>>>(M, wb0, b0, actA);
  k_conv<2><<<dim3(16, 32), 256, 0, stream>>>(actA, wb1, b1, actB);
  k_conv<4><<<dim3(16, 32), 256, 0, stream>>>(actB, wb2, b2, actA);
  k_conv<8><<<dim3(16, 32), 256, 0, stream>>>(actA, wb3, b3, actB);
  k_ugemm<<<dim3(16, 32, 2), 256, 0, stream>>>(actB, wce, bce, u);
  k_scan<<<32, 256, 0, stream>>>(Am, u, hbar);
  k_post<<<32, 256, 0, stream>>>(M, hbar, mw1, mb1, mw2, mb2, mw3, mb3,
                                 fw1, fb1, fw2, fb2, opw, opb,
                                 cw1, cb1, cw2, cb2, out);
}

// Round 12
// 1406.104 us; speedup vs baseline: 1.2401x; 1.2401x over previous
//
#include <hip/hip_runtime.h>
#include <cmath>

// ---------------------------------------------------------------------------
// CausalStream: conv frontend (4 dilated causal convs) -> folded enc+ip GEMM
// -> sequential gelu-SSM scan -> pooled/cls heads + metanet/frontdoor path.
// B=32, D=6, T=2048, FH=128, ENC=128, H=256, CONF=64, NC=10, K=5
// Verified round-5 build (1406.7 us total r5; reproduced 1409.7 us r10).
// Scan structural floor (measured r0-r11): step = ~120 read + 512 MFMA-pipe
// (invariant under wave count/chains/sched/dot-path) + ~730 in-order tail.
// ---------------------------------------------------------------------------

typedef __bf16 bf16_t;
typedef bf16_t bf16x8 __attribute__((ext_vector_type(8)));
typedef float f32x4 __attribute__((ext_vector_type(4)));

__device__ __forceinline__ f32x4 mfma16(bf16x8 a, bf16x8 b, f32x4 c) {
  return __builtin_amdgcn_mfma_f32_16x16x32_bf16(a, b, c, 0, 0, 0);
}

// Fast erf-gelu: Abramowitz-Stegun 7.1.26 (|erf err| <= 1.5e-7), branch-free.
__device__ __forceinline__ float gelu_f(float x) {
  float a = x * 0.70710678118654752440f;
  float z = fabsf(a);
  float t = __builtin_amdgcn_rcpf(1.0f + 0.3275911f * z);
  float p = t * (0.254829592f +
            t * (-0.284496736f +
            t * (1.421413741f +
            t * (-1.453152027f +
            t * 1.061405429f))));
  float e = __expf(-z * z);
  float erf_a = __builtin_copysignf(1.0f - p * e, a);
  return 0.5f * x * (1.0f + erf_a);
}

// ---------------------------------------------------------------------------
// k_prep: conv-weight repack (blocks 0..975) + enc/ip fold (blocks 976..1103).
// ---------------------------------------------------------------------------
__global__ void k_prep(const float* __restrict__ w0, const float* __restrict__ w1,
                       const float* __restrict__ w2, const float* __restrict__ w3,
                       const float* __restrict__ ip_w, const float* __restrict__ enc_w,
                       const float* __restrict__ enc_b, const float* __restrict__ ip_b,
                       const float* __restrict__ sbias,
                       bf16_t* __restrict__ wb0, bf16_t* __restrict__ wb1,
                       bf16_t* __restrict__ wb2, bf16_t* __restrict__ wb3,
                       bf16_t* __restrict__ wce, float* __restrict__ bce) {
  int bid = blockIdx.x;
  if (bid >= 976) {
    // W_ce[h][c] = sum_e ip_w[h][e]*enc_w[e][c]
    int idx = (bid - 976) * 256 + threadIdx.x;  // 0..32767
    int h = idx >> 7, c = idx & 127;
    float s = 0.f;
    for (int e = 0; e < 128; ++e) s += ip_w[h * 128 + e] * enc_w[e * 128 + c];
    wce[h * 128 + c] = (bf16_t)s;
    if (c == 0) {
      float bv = 0.f;
      for (int e = 0; e < 128; ++e) bv += ip_w[h * 128 + e] * enc_b[e];
      bce[h] = bv + ip_b[h] + sbias[h];
    }
    return;
  }
  int idx = bid * 256 + threadIdx.x;
  if (idx < 128 * 32) {
    int o = idx >> 5, k = idx & 31;
    float v = 0.f;
    if (k < 30) { int i = k / 5, kk = k - i * 5; v = w0[(o * 6 + i) * 5 + kk]; }
    wb0[idx] = (bf16_t)v;
    return;
  }
  int e = idx - 128 * 32;
  if (e < 3 * 5 * 128 * 128) {
    int layer = e / (5 * 128 * 128);
    int r = e - layer * (5 * 128 * 128);
    int ks = r / 16384;
    int o = (r >> 7) & 127;
    int i = r & 127;
    const float* w = layer == 0 ? w1 : layer == 1 ? w2 : w3;
    bf16_t* wb = layer == 0 ? wb1 : layer == 1 ? wb2 : wb3;
    wb[r] = (bf16_t)w[(o * 128 + i) * 5 + ks];
  }
}

// ---------------------------------------------------------------------------
// conv0: M (B,6,T) fp32 -> act (B,T,128) bf16.  K-dim = 6*5 padded to 32.
// ---------------------------------------------------------------------------
__global__ __launch_bounds__(256) void k_conv0(const float* __restrict__ M,
                                               const bf16_t* __restrict__ wb0,
                                               const float* __restrict__ b0,
                                               bf16_t* __restrict__ out) {
  __shared__ float raw[6][136];
  __shared__ bf16_t Xe[128 * 40];
  const int tid = threadIdx.x;
  const int b = blockIdx.y, t0 = blockIdx.x * 128;
  for (int id = tid; id < 6 * 132; id += 256) {
    int i = id / 132, j = id - i * 132;
    int t = t0 - 4 + j;
    raw[i][j] = (t >= 0) ? M[((size_t)b * 6 + i) * 2048 + t] : 0.f;
  }
  __syncthreads();
  for (int id = tid; id < 128 * 32; id += 256) {
    int tl = id >> 5, k = id & 31;
    float v = 0.f;
    if (k < 30) { int i = k / 5, kk = k - i * 5; v = raw[i][tl + kk]; }
    Xe[tl * 40 + k] = (bf16_t)v;
  }
  __syncthreads();
  const int w = tid >> 6, lane = tid & 63, q = lane >> 4, l15 = lane & 15;
  const int k0 = q * 8;
  const f32x4 z4 = {0.f, 0.f, 0.f, 0.f};
  f32x4 acc[2][8];
#pragma unroll
  for (int mt = 0; mt < 2; ++mt)
#pragma unroll
    for (int nt = 0; nt < 8; ++nt) acc[mt][nt] = z4;
  bf16x8 af[2];
#pragma unroll
  for (int mt = 0; mt < 2; ++mt)
    af[mt] = *(const bf16x8*)&Xe[(w * 32 + mt * 16 + l15) * 40 + k0];
#pragma unroll
  for (int nt = 0; nt < 8; ++nt) {
    bf16x8 bf = *(const bf16x8*)&wb0[(nt * 16 + l15) * 32 + k0];
#pragma unroll
    for (int mt = 0; mt < 2; ++mt) acc[mt][nt] = mfma16(af[mt], bf, acc[mt][nt]);
  }
#pragma unroll
  for (int nt = 0; nt < 8; ++nt) {
    const int o = nt * 16 + l15;
    const float bias = b0[o];
#pragma unroll
    for (int mt = 0; mt < 2; ++mt) {
#pragma unroll
      for (int r = 0; r < 4; ++r) {
        int t = t0 + w * 32 + mt * 16 + q * 4 + r;
        float v = acc[mt][nt][r] + bias;
        out[((size_t)b * 2048 + t) * 128 + o] = (bf16_t)(v > 0.f ? v : 0.f);
      }
    }
  }
}

// ---------------------------------------------------------------------------
// conv layers 1..3 (verified 128-tile): act (B,T,128) bf16 -> act bf16,
// kernel 5, dilation DIL, causal.  Implicit GEMM.
// ---------------------------------------------------------------------------
template <int DIL>
__global__ __launch_bounds__(256) void k_conv(const bf16_t* __restrict__ in,
                                              const bf16_t* __restrict__ wb,
                                              const float* __restrict__ bias,
                                              bf16_t* __restrict__ out) {
  __shared__ bf16_t Xs[160 * 136];  // rows r <-> t = t0 + r - 32, pitch-padded
  const int tid = threadIdx.x;
  const int b = blockIdx.y, t0 = blockIdx.x * 128;
  const bf16_t* src = in + (size_t)b * 2048 * 128;
  for (int id = tid; id < 160 * 16; id += 256) {
    int r = id >> 4, ck = id & 15;
    int t = t0 + r - 32;
    int4 v = make_int4(0, 0, 0, 0);
    if (t >= 0) v = *(const int4*)(src + (size_t)t * 128 + ck * 8);
    *(int4*)&Xs[r * 136 + ck * 8] = v;
  }
  __syncthreads();
  const int w = tid >> 6, lane = tid & 63, q = lane >> 4, l15 = lane & 15;
  const f32x4 z4 = {0.f, 0.f, 0.f, 0.f};
  f32x4 acc[2][8];
#pragma unroll
  for (int mt = 0; mt < 2; ++mt)
#pragma unroll
    for (int nt = 0; nt < 8; ++nt) acc[mt][nt] = z4;
#pragma unroll
  for (int ks = 0; ks < 5; ++ks) {
    const int shift = (4 - ks) * DIL;
#pragma unroll
    for (int kt = 0; kt < 4; ++kt) {
      const int k0 = kt * 32 + q * 8;
      bf16x8 af[2];
#pragma unroll
      for (int mt = 0; mt < 2; ++mt)
        af[mt] = *(const bf16x8*)&Xs[(32 + w * 32 + mt * 16 + l15 - shift) * 136 + k0];
#pragma unroll
      for (int nt = 0; nt < 8; ++nt) {
        bf16x8 bf = *(const bf16x8*)&wb[((size_t)ks * 128 + nt * 16 + l15) * 128 + k0];
#pragma unroll
        for (int mt = 0; mt < 2; ++mt) acc[mt][nt] = mfma16(af[mt], bf, acc[mt][nt]);
      }
    }
  }
#pragma unroll
  for (int nt = 0; nt < 8; ++nt) {
    const int o = nt * 16 + l15;
    const float bv = bias[o];
#pragma unroll
    for (int mt = 0; mt < 2; ++mt) {
#pragma unroll
      for (int r = 0; r < 4; ++r) {
        int t = t0 + w * 32 + mt * 16 + q * 4 + r;
        float v = acc[mt][nt][r] + bv;
        out[((size_t)b * 2048 + t) * 128 + o] = (bf16_t)(v > 0.f ? v : 0.f);
      }
    }
  }
}

// ---------------------------------------------------------------------------
// u-GEMM: u[b][t][h] = act3[b][t][:] @ W_ce[h][:] + b_ce[h]   (bf16 out)
// ---------------------------------------------------------------------------
__global__ __launch_bounds__(256) void k_ugemm(const bf16_t* __restrict__ in,
                                               const bf16_t* __restrict__ wce,
                                               const float* __restrict__ bce,
                                               bf16_t* __restrict__ u) {
  __shared__ bf16_t Xs[128 * 136];
  const int tid = threadIdx.x;
  const int b = blockIdx.y, t0 = blockIdx.x * 128, hh = blockIdx.z;
  const bf16_t* src = in + (size_t)b * 2048 * 128;
  for (int id = tid; id < 128 * 16; id += 256) {
    int r = id >> 4, ck = id & 15;
    *(int4*)&Xs[r * 136 + ck * 8] = *(const int4*)(src + (size_t)(t0 + r) * 128 + ck * 8);
  }
  __syncthreads();
  const int w = tid >> 6, lane = tid & 63, q = lane >> 4, l15 = lane & 15;
  const f32x4 z4 = {0.f, 0.f, 0.f, 0.f};
  f32x4 acc[2][8];
#pragma unroll
  for (int mt = 0; mt < 2; ++mt)
#pragma unroll
    for (int nt = 0; nt < 8; ++nt) acc[mt][nt] = z4;
#pragma unroll
  for (int kt = 0; kt < 4; ++kt) {
    const int k0 = kt * 32 + q * 8;
    bf16x8 af[2];
#pragma unroll
    for (int mt = 0; mt < 2; ++mt)
      af[mt] = *(const bf16x8*)&Xs[(w * 32 + mt * 16 + l15) * 136 + k0];
#pragma unroll
    for (int nt = 0; nt < 8; ++nt) {
      bf16x8 bf = *(const bf16x8*)&wce[((size_t)hh * 128 + nt * 16 + l15) * 128 + k0];
#pragma unroll
      for (int mt = 0; mt < 2; ++mt) acc[mt][nt] = mfma16(af[mt], bf, acc[mt][nt]);
    }
  }
#pragma unroll
  for (int nt = 0; nt < 8; ++nt) {
    const int h = hh * 128 + nt * 16 + l15;
    const float bv = bce[h];
#pragma unroll
    for (int mt = 0; mt < 2; ++mt) {
#pragma unroll
      for (int r = 0; r < 4; ++r) {
        int t = t0 + w * 32 + mt * 16 + q * 4 + r;
        u[((size_t)b * 2048 + t) * 256 + h] = (bf16_t)(acc[mt][nt][r] + bv);
      }
    }
  }
}

// ---------------------------------------------------------------------------
// Sequential scan: h_{t} = gelu(A @ h_{t-1} + u_t).  One block per sample.
// Verified round-5 structure (1060-1063 us): lgkm-only barrier + 2-deep u
// prefetch, SGB-pinned [8 DS_READ][32 MFMA], u as MFMA C-in (lane (q,l15)
// sets tile q reg 0 = row 4q col l15 — the element it reads back), hbar
// accumulated past the barrier.
// ---------------------------------------------------------------------------
__global__ __launch_bounds__(256, 1) void k_scan(const float* __restrict__ Am,
                                                 const bf16_t* __restrict__ u,
                                                 float* __restrict__ hbarOut) {
  __shared__ bf16_t hb[2][256];
  const int b = blockIdx.x;
  const int tid = threadIdx.x;
  const int w = tid >> 6, lane = tid & 63, q = lane >> 4, l15 = lane & 15;

  // B-fragments: B[k=j][n=c] = A[c][j], c = w*64 + nt*16 + l15, j = kt*32+q*8+e
  bf16x8 bfr[4][8];
#pragma unroll
  for (int nt = 0; nt < 4; ++nt) {
    const int c = w * 64 + nt * 16 + l15;
#pragma unroll
    for (int kt = 0; kt < 8; ++kt) {
      const float* ap = Am + (size_t)c * 256 + kt * 32 + q * 8;
      f32x4 p0 = *(const f32x4*)ap;
      f32x4 p1 = *(const f32x4*)(ap + 4);
      bf16x8 v;
      v[0] = (bf16_t)p0[0]; v[1] = (bf16_t)p0[1]; v[2] = (bf16_t)p0[2]; v[3] = (bf16_t)p0[3];
      v[4] = (bf16_t)p1[0]; v[5] = (bf16_t)p1[1]; v[6] = (bf16_t)p1[2]; v[7] = (bf16_t)p1[3];
      bfr[nt][kt] = v;
    }
  }
  hb[0][tid] = (bf16_t)0.f;
  hb[1][tid] = (bf16_t)0.f;
  const bf16_t* up = u + (size_t)b * 2048 * 256 + tid;
  float hbar = 0.f;
  bf16_t ua = up[0];
  bf16_t ub = up[256];
  __syncthreads();

  const f32x4 z4 = {0.f, 0.f, 0.f, 0.f};

#define SCAN_STEP(RD, WR, UREG)                                   \
  {                                                               \
    bf16x8 af[8];                                                 \
    _Pragma("unroll")                                             \
    for (int kt = 0; kt < 8; ++kt)                                \
      af[kt] = *(const bf16x8*)&hb[RD][kt * 32 + q * 8];          \
    float uin = (float)(UREG);                                    \
    f32x4 acc[4];                                                 \
    _Pragma("unroll")                                             \
    for (int nt = 0; nt < 4; ++nt) {                              \
      acc[nt] = z4;                                               \
      acc[nt][0] = (q == nt) ? uin : 0.f;                         \
    }                                                             \
    _Pragma("unroll")                                             \
    for (int kt = 0; kt < 8; ++kt) {                              \
      _Pragma("unroll")                                           \
      for (int nt = 0; nt < 4; ++nt)                              \
        acc[nt] = mfma16(af[kt], bfr[nt][kt], acc[nt]);           \
    }                                                             \
    __builtin_amdgcn_sched_group_barrier(0x100, 8, 0);            \
    __builtin_amdgcn_sched_group_barrier(0x008, 32, 0);           \
    float y = (q == 0) ? acc[0][0] : (q == 1) ? acc[1][0]         \
            : (q == 2) ? acc[2][0] : acc[3][0];                   \
    float g = gelu_f(y);                                          \
    hb[WR][tid] = (bf16_t)g;                                      \
    asm volatile("s_waitcnt lgkmcnt(0)" ::: "memory");            \
    __builtin_amdgcn_s_barrier();                                 \
    __builtin_amdgcn_sched_barrier(0);                            \
    hbar += g;                                                    \
  }

  for (int t = 0; t < 2048; t += 2) {
    bf16_t ua2 = (t + 2 < 2048) ? up[(size_t)(t + 2) * 256] : (bf16_t)0.f;
    SCAN_STEP(0, 1, ua)
    bf16_t ub2 = (t + 3 < 2048) ? up[(size_t)(t + 3) * 256] : (bf16_t)0.f;
    SCAN_STEP(1, 0, ub)
    ua = ua2;
    ub = ub2;
  }
#undef SCAN_STEP

  hbarOut[b * 256 + tid] = hbar * (1.f / 2048.f);
}

// ---------------------------------------------------------------------------
// k_post: metanet stats + metanet/frontdoor MLPs + pooled/cls head, fused.
// One block per sample, 256 threads.  Runs after k_scan (needs hbar).
// ---------------------------------------------------------------------------
__global__ __launch_bounds__(256) void k_post(
    const float* __restrict__ M, const float* __restrict__ hbar,
    const float* __restrict__ w1, const float* __restrict__ b1,
    const float* __restrict__ w2, const float* __restrict__ b2,
    const float* __restrict__ w3, const float* __restrict__ b3,
    const float* __restrict__ f1, const float* __restrict__ fb1,
    const float* __restrict__ f2, const float* __restrict__ fb2,
    const float* __restrict__ op_w, const float* __restrict__ op_b,
    const float* __restrict__ cw1, const float* __restrict__ cb1,
    const float* __restrict__ cw2, const float* __restrict__ cb2,
    float* __restrict__ out) {
  const int b = blockIdx.x, tid = threadIdx.x;
  const int w = tid >> 6, lane = tid & 63;
  __shared__ float s12[12], z1[64], z2[128], ch[64], a1[128], adjs[256];
  __shared__ float hs[256], ps[256], hid[256];
  __shared__ float as_[4], ass_[4];
  // stats: mean & unbiased std per channel
  for (int c = 0; c < 6; ++c) {
    const float* p = M + ((size_t)b * 6 + c) * 2048;
    float s = 0.f, ss = 0.f;
    for (int t = tid; t < 2048; t += 256) { float v = p[t]; s += v; ss += v * v; }
    for (int o = 32; o > 0; o >>= 1) { s += __shfl_down(s, o, 64); ss += __shfl_down(ss, o, 64); }
    if (lane == 0) { as_[w] = s; ass_[w] = ss; }
    __syncthreads();
    if (tid == 0) {
      s = as_[0] + as_[1] + as_[2] + as_[3];
      ss = ass_[0] + ass_[1] + ass_[2] + ass_[3];
      float mean = s * (1.f / 2048.f);
      float var = (ss - 2048.f * mean * mean) * (1.f / 2047.f);
      if (var < 0.f) var = 0.f;
      s12[c] = mean;
      s12[6 + c] = sqrtf(var);
    }
    __syncthreads();
  }
  // metanet
  if (tid < 64) {
    float v = b1[tid];
    for (int e = 0; e < 12; ++e) v += w1[tid * 12 + e] * s12[e];
    z1[tid] = v > 0.f ? v : 0.f;
  }
  __syncthreads();
  if (tid < 128) {
    float v = b2[tid];
    for (int e = 0; e < 64; ++e) v += w2[tid * 64 + e] * z1[e];
    z2[tid] = v > 0.f ? v : 0.f;
  }
  __syncthreads();
  if (tid < 64) {
    float v = b3[tid];
    for (int e = 0; e < 128; ++e) v += w3[tid * 128 + e] * z2[e];
    ch[tid] = v;
    out[16704 + b * 64 + tid] = v;  // conf_hat
  }
  __syncthreads();
  if (tid < 128) {
    float v = fb1[tid];
    for (int e = 0; e < 64; ++e) v += f1[tid * 64 + e] * ch[e];
    a1[tid] = v > 0.f ? v : 0.f;
  }
  __syncthreads();
  {
    float v = fb2[tid];
    for (int e = 0; e < 128; ++e) v += f2[tid * 128 + e] * a1[e];
    adjs[tid] = v;  // self-read below, no sync needed
  }
  // head
  hs[tid] = hbar[b * 256 + tid];
  __syncthreads();
  float v = op_b[tid];
  for (int h = 0; h < 256; ++h) v += op_w[tid * 256 + h] * hs[h];
  out[320 + b * 256 + tid] = v;                    // pooled
  out[8512 + b * 256 + tid] = v - adjs[tid];       // corrected
  ps[tid] = v;
  __syncthreads();
  float hv = cb1[tid];
  for (int h = 0; h < 256; ++h) hv += cw1[tid * 256 + h] * ps[h];
  hid[tid] = hv > 0.f ? hv : 0.f;
  __syncthreads();
  if (tid < 10) {
    float lv = cb2[tid];
    for (int h = 0; h < 256; ++h) lv += cw2[tid * 256 + h] * hid[h];
    out[b * 10 + tid] = lv;  // logits
  }
}

// ---------------------------------------------------------------------------
extern "C" void kernel_launch(void* const* d_in, const int* in_sizes, int n_in,
                              void* d_out, int out_size, void* d_ws, size_t ws_size,
                              hipStream_t stream) {
  (void)in_sizes; (void)n_in; (void)out_size; (void)ws_size;
  const float* M    = (const float*)d_in[0];
  const float* w0   = (const float*)d_in[1];  const float* b0  = (const float*)d_in[2];
  const float* w1   = (const float*)d_in[3];  const float* b1  = (const float*)d_in[4];
  const float* w2   = (const float*)d_in[5];  const float* b2  = (const float*)d_in[6];
  const float* w3   = (const float*)d_in[7];  const float* b3  = (const float*)d_in[8];
  const float* encw = (const float*)d_in[9];  const float* encb = (const float*)d_in[10];
  const float* Am   = (const float*)d_in[11];
  const float* ipw  = (const float*)d_in[12]; const float* ipb = (const float*)d_in[13];
  const float* sb   = (const float*)d_in[14];
  const float* opw  = (const float*)d_in[15]; const float* opb = (const float*)d_in[16];
  const float* cw1  = (const float*)d_in[17]; const float* cb1 = (const float*)d_in[18];
  const float* cw2  = (const float*)d_in[19]; const float* cb2 = (const float*)d_in[20];
  const float* mw1  = (const float*)d_in[21]; const float* mb1 = (const float*)d_in[22];
  const float* mw2  = (const float*)d_in[23]; const float* mb2 = (const float*)d_in[24];
  const float* mw3  = (const float*)d_in[25]; const float* mb3 = (const float*)d_in[26];
  const float* fw1  = (const float*)d_in[27]; const float* fb1 = (const float*)d_in[28];
  const float* fw2  = (const float*)d_in[29]; const float* fb2 = (const float*)d_in[30];
  float* out = (float*)d_out;

  char* ws = (char*)d_ws;
  bf16_t* wb0  = (bf16_t*)(ws + 0);          // 8192
  bf16_t* wb1  = (bf16_t*)(ws + 8192);       // 163840
  bf16_t* wb2  = (bf16_t*)(ws + 172032);     // 163840
  bf16_t* wb3  = (bf16_t*)(ws + 335872);     // 163840
  bf16_t* wce  = (bf16_t*)(ws + 499712);     // 65536
  float*  bce  = (float*) (ws + 565248);     // 1024
  float*  hbar = (float*) (ws + 566272);     // 32768
  bf16_t* actA = (bf16_t*)(ws + 633856);     // 16 MB
  bf16_t* actB = (bf16_t*)(ws + 17411072);   // 16 MB
  bf16_t* u    = (bf16_t*)(ws + 34188288);   // 32 MB  (total ~64.6 MB)

  k_prep<<<1104, 256, 0, stream>>>(w0, w1, w2, w3, ipw, encw, encb, ipb, sb,
                                   wb0, wb1, wb2, wb3, wce, bce);
  k_conv0<<<dim3(16, 32), 256, 0, stream>>>(M, wb0, b0, actA);
  k_conv<2><<<dim3(16, 32), 256, 0, stream>>>(actA, wb1, b1, actB);
  k_conv<4><<<dim3(16, 32), 256, 0, stream>>>(actB, wb2, b2, actA);
  k_conv<8><<<dim3(16, 32), 256, 0, stream>>>(actA, wb3, b3, actB);
  k_ugemm<<<dim3(16, 32, 2), 256, 0, stream>>>(actB, wce, bce, u);
  k_scan<<<32, 256, 0, stream>>>(Am, u, hbar);
  k_post<<<32, 256, 0, stream>>>(M, hbar, mw1, mb1, mw2, mb2, mw3, mb3,
                                 fw1, fb1, fw2, fb2, opw, opb,
                                 cw1, cb1, cw2, cb2, out);
}